// Round 1
// baseline (17446.523 us; speedup 1.0000x reference)
//
#include <hip/hip_runtime.h>
#include <cstdint>
#include <cstddef>

#define DEVI __device__ __forceinline__

typedef __attribute__((ext_vector_type(8))) short short8;
typedef __attribute__((ext_vector_type(4))) float floatx4;

DEVI float bf2f(unsigned short u) { union { unsigned int i; float f; } v; v.i = ((unsigned int)u) << 16; return v.f; }
DEVI unsigned short f2bf(float f) {
  union { float f; unsigned int i; } v; v.f = f;
  unsigned int r = v.i + 0x7fffu + ((v.i >> 16) & 1u);
  return (unsigned short)(r >> 16);
}
DEVI float fsig(float x) { return 1.f / (1.f + __expf(-x)); }
DEVI float ftanh(float x) { return 1.f - 2.f / (__expf(2.f * x) + 1.f); }

struct PP {
  const float *c1_0, *c2_0;
  const float *att_b, *dhp_b, *corr_w, *corr_b, *lt_b;
  const float *b_ih1, *b_hh1, *b_ih2, *b_hh2;
  const int* masks;
  float* out;
  unsigned int* SY; float* q0acc;
  const unsigned short* ench; unsigned short* proj; const unsigned short* caps;
  const unsigned short *W1t, *W2t, *dhpWt, *ltWt, *attWt;
  unsigned short* at; unsigned short* h1b; unsigned short* h2b; float* q;
};

// ---- hierarchical device-wide barrier: 8 groups x 32 blocks ----
DEVI void gbar(unsigned int* SY, int round) {
  __syncthreads();
  if (threadIdx.x == 0) {
    __threadfence();
    const int grp = blockIdx.x & 7;
    const unsigned v = atomicAdd(&SY[16 + grp * 16], 1u);
    if (v == (unsigned)(round * 32 + 31)) {
      const unsigned w = atomicAdd(&SY[0], 1u);
      if (w == (unsigned)(round * 8 + 7)) {
        __threadfence();
#pragma unroll
        for (int i = 0; i < 8; ++i)
          __hip_atomic_store(&SY[160 + i * 16], (unsigned)(round + 1),
                             __ATOMIC_RELAXED, __HIP_MEMORY_SCOPE_AGENT);
      }
    }
    while (__hip_atomic_load(&SY[160 + grp * 16], __ATOMIC_RELAXED,
                             __HIP_MEMORY_SCOPE_AGENT) < (unsigned)(round + 1))
      __builtin_amdgcn_s_sleep(1);
    __threadfence();
  }
  __syncthreads();
}

DEVI void zero_g(float* g) {
  for (int i = threadIdx.x; i < 128 * 17; i += 1024) g[i] = 0.f;
}

// Each of 16 waves takes a distinct K-slice (nsteps MFMA k-steps of 32) over all 8
// M-tiles x one 16-col N-tile; partials combined via LDS fp32 atomics into g[128][17].
template <typename AL>
DEVI void gemm_g(float* g, const unsigned short* Wtile, int ldw, int nsteps, AL aload) {
  const int tid = threadIdx.x, wave = tid >> 6, lane = tid & 63;
  const unsigned short* wrow = Wtile + (size_t)(lane & 15) * ldw;
  const int kq = ((lane >> 4) << 3);
  const int k0w = wave * (nsteps << 5);
  floatx4 acc[8];
#pragma unroll
  for (int m = 0; m < 8; ++m) acc[m] = (floatx4){0.f, 0.f, 0.f, 0.f};
  for (int s = 0; s < nsteps; ++s) {
    const int k = k0w + (s << 5) + kq;
    short8 bf = *(const short8*)(wrow + k);
#pragma unroll
    for (int m = 0; m < 8; ++m) {
      short8 af = aload((m << 4) + (lane & 15), k);
      acc[m] = __builtin_amdgcn_mfma_f32_16x16x32_bf16(af, bf, acc[m], 0, 0, 0);
    }
  }
  const int col = lane & 15, r0 = ((lane >> 4) << 2);
#pragma unroll
  for (int m = 0; m < 8; ++m)
#pragma unroll
    for (int r = 0; r < 4; ++r)
      atomicAdd(&g[((m << 4) + r0 + r) * 17 + col], acc[m][r]);
}

DEVI void out_stage(const PP& p, float* g, int ot, int ob) {
  zero_g(g); __syncthreads();
  const unsigned short* h1 = p.h1b + (((unsigned)ot & 1u) << 17);
  auto al = [&](int row, int k) -> short8 {
    return *(const short8*)(h1 + ((size_t)row << 10) + k);
  };
  gemm_g(g, p.ltWt + (size_t)ob * 16 * 1024, 1024, 2, al);
  __syncthreads();
  for (int e = threadIdx.x; e < 2048; e += 1024) {
    const int b = e >> 4, col = e & 15, n = ob * 16 + col;
    p.out[(size_t)ot * 131072 + (b << 10) + n] = ftanh(g[b * 17 + col] + p.lt_b[n]);
  }
}

__global__ __launch_bounds__(1024) void persist(PP p) {
  __shared__ float g[128 * 17];
  __shared__ float c1s[512], c2s[512];
  __shared__ float bias1[16], bias2[16];
  __shared__ float q_s[512], corr_s[512];
  __shared__ float alpha_s[128], e_s[128];
  __shared__ float redv[2];
  const int tid = threadIdx.x, blk = blockIdx.x;
  const int wave = tid >> 6, lane = tid & 63;

  // ---- pre-loop: enc_proj = ench @ att_W + att_b (bf16 MFMA, all 256 blocks) ----
  {
    const int mw = wave & 3, ng = wave >> 2;
    const int mtile = blk * 4 + mw;
    const int mrow = mtile * 16 + (lane & 15);
    const int kq = ((lane >> 4) << 3);
    floatx4 acc[8];
#pragma unroll
    for (int nt = 0; nt < 8; ++nt) acc[nt] = (floatx4){0.f, 0.f, 0.f, 0.f};
    for (int s = 0; s < 32; ++s) {
      const int k = (s << 5) + kq;
      short8 af = *(const short8*)(p.ench + (size_t)mrow * 1024 + k);
#pragma unroll
      for (int nt = 0; nt < 8; ++nt) {
        short8 bf = *(const short8*)(p.attWt + (size_t)(ng * 128 + nt * 16 + (lane & 15)) * 1024 + k);
        acc[nt] = __builtin_amdgcn_mfma_f32_16x16x32_bf16(af, bf, acc[nt], 0, 0, 0);
      }
    }
#pragma unroll
    for (int nt = 0; nt < 8; ++nt)
#pragma unroll
      for (int r = 0; r < 4; ++r) {
        const int rowg = mtile * 16 + ((lane >> 4) << 2) + r;
        const int col = ng * 128 + nt * 16 + (lane & 15);
        p.proj[(size_t)rowg * 512 + col] = f2bf(acc[nt][r] + p.att_b[col]);
      }
  }
  // q init for t=0: h_prev0 = ones/1024 -> q0 = colmean(dhp_W) + dhp_b, broadcast rows
  if (blk < 128) {
    for (int n = tid; n < 512; n += 1024)
      p.q[blk * 512 + n] = p.q0acc[n] * (1.f / 1024.f) + p.dhp_b[n];
  }
  if (tid < 512) {
    const int b = tid >> 2, c = tid & 3;
    c1s[tid] = p.c1_0[b * 1024 + blk * 4 + c];
    c2s[tid] = p.c2_0[b * 1024 + blk * 4 + c];
  }
  if (tid < 16) {
    const int gg = tid >> 2, c = tid & 3;
    const int oc = gg * 1024 + blk * 4 + c;
    bias1[tid] = p.b_ih1[oc] + p.b_hh1[oc];
    bias2[tid] = p.b_ih2[oc] + p.b_hh2[oc];
  }
  if (blk >= 64 && blk < 192 && tid < 512) corr_s[tid] = p.corr_w[tid];

  int round = 0;
  gbar(p.SY, round); ++round;

  for (int t = 0; t < 64; ++t) {
    // ======== Stage 1: q_t (blk 0..31) | attention_t (blk 64..191) | out_{t-1} (blk 192..255) ========
    if (blk < 32) {
      if (t > 0) {
        zero_g(g); __syncthreads();
        const unsigned short* h2p = p.h2b + ((((unsigned)t + 1u) & 1u) << 17);
        auto al = [&](int row, int k) -> short8 {
          return *(const short8*)(h2p + ((size_t)row << 10) + k);
        };
        gemm_g(g, p.dhpWt + (size_t)blk * 16 * 1024, 1024, 2, al);
        __syncthreads();
        for (int e = tid; e < 2048; e += 1024) {
          const int b = e >> 4, col = e & 15, n = blk * 16 + col;
          p.q[b * 512 + n] = g[b * 17 + col] + p.dhp_b[n];
        }
        __syncthreads();
        if (tid == 0) { __threadfence(); atomicAdd(&p.SY[300], 1u); }
      }
    } else if (blk >= 64 && blk < 192) {
      const int b = blk - 64;
      if (t > 0) {
        if (tid == 0) {
          while (__hip_atomic_load(&p.SY[300], __ATOMIC_RELAXED,
                                   __HIP_MEMORY_SCOPE_AGENT) < (unsigned)(32 * t))
            __builtin_amdgcn_s_sleep(1);
          __threadfence();
        }
        __syncthreads();
      }
      for (int n = tid; n < 512; n += 1024) q_s[n] = p.q[b * 512 + n];
      __syncthreads();
      // e[l] = corr . tanh(proj[b,l,:] + q) ; 8 lanes per l
      {
        const int l = tid >> 3, l8 = tid & 7;
        const unsigned short* pp_ = p.proj + ((size_t)(b * 128 + l)) * 512 + l8 * 64;
        float acc = 0.f;
#pragma unroll 2
        for (int j = 0; j < 8; ++j) {
          short8 v = *(const short8*)(pp_ + j * 8);
#pragma unroll
          for (int i = 0; i < 8; ++i) {
            const int ap = l8 * 64 + j * 8 + i;
            acc += ftanh(bf2f((unsigned short)v[i]) + q_s[ap]) * corr_s[ap];
          }
        }
        acc += __shfl_down(acc, 4, 8);
        acc += __shfl_down(acc, 2, 8);
        acc += __shfl_down(acc, 1, 8);
        if (l8 == 0) {
          acc += p.corr_b[0];
          if (p.masks[b * 128 + l] != 0) acc = -1e30f;
          e_s[l] = acc;
        }
      }
      __syncthreads();
      if (wave == 0) {
        float m0 = fmaxf(e_s[lane], e_s[lane + 64]);
#pragma unroll
        for (int off = 32; off; off >>= 1) m0 = fmaxf(m0, __shfl_xor(m0, off));
        const float a0 = __expf(e_s[lane] - m0), a1 = __expf(e_s[lane + 64] - m0);
        alpha_s[lane] = a0; alpha_s[lane + 64] = a1;
        float s = a0 + a1;
#pragma unroll
        for (int off = 32; off; off >>= 1) s += __shfl_xor(s, off);
        if (lane == 0) redv[0] = 1.f / s;
      }
      __syncthreads();
      {
        const float inv = redv[0];
        const unsigned short* pe = p.ench + ((size_t)b << 17) + tid;
        float acc = 0.f;
#pragma unroll 4
        for (int l = 0; l < 128; ++l) acc += alpha_s[l] * bf2f(pe[(size_t)l << 10]);
        p.at[(b << 10) + tid] = f2bf(acc * inv);
      }
    } else if (blk >= 192) {
      if (t > 0) out_stage(p, g, t - 1, blk - 192);
    }
    gbar(p.SY, round); ++round;

    // ======== Stage 2: G1 = [x_t | a_t | h1_{t-1}] @ W1 -> LSTM1 (all blocks) ========
    {
      zero_g(g); __syncthreads();
      const unsigned short* caps_t = p.caps + ((size_t)t << 16);
      const unsigned short* h1p = p.h1b + ((((unsigned)t + 1u) & 1u) << 17);
      const unsigned short* at_ = p.at;
      auto al = [&](int row, int k) -> short8 {
        const unsigned short* q_;
        if (k < 512)       q_ = caps_t + ((size_t)row << 9) + k;
        else if (k < 1536) q_ = at_ + ((size_t)row << 10) + (k - 512);
        else               q_ = h1p + ((size_t)row << 10) + (k - 1536);
        return *(const short8*)q_;
      };
      gemm_g(g, p.W1t + (size_t)blk * 16 * 2560, 2560, 5, al);
      __syncthreads();
      if (tid < 512) {
        const int b = tid >> 2, c = tid & 3;
        const float gi = g[b * 17 + c] + bias1[c];
        const float gf = g[b * 17 + 4 + c] + bias1[4 + c];
        const float gg = g[b * 17 + 8 + c] + bias1[8 + c];
        const float go = g[b * 17 + 12 + c] + bias1[12 + c];
        const float cn = fsig(gf) * c1s[tid] + fsig(gi) * ftanh(gg);
        c1s[tid] = cn;
        p.h1b[(((unsigned)t & 1u) << 17) + (b << 10) + blk * 4 + c] = f2bf(fsig(go) * ftanh(cn));
      }
    }
    gbar(p.SY, round); ++round;

    // ======== Stage 3: G2 = [h1_t | h2_{t-1}] @ W2 -> LSTM2 (all blocks) ========
    {
      zero_g(g); __syncthreads();
      const unsigned short* h1c = p.h1b + (((unsigned)t & 1u) << 17);
      const unsigned short* h2p = p.h2b + ((((unsigned)t + 1u) & 1u) << 17);
      auto al = [&](int row, int k) -> short8 {
        const unsigned short* q_;
        if (k < 1024) q_ = h1c + ((size_t)row << 10) + k;
        else          q_ = h2p + ((size_t)row << 10) + (k - 1024);
        return *(const short8*)q_;
      };
      gemm_g(g, p.W2t + (size_t)blk * 16 * 2048, 2048, 4, al);
      __syncthreads();
      if (tid < 512) {
        const int b = tid >> 2, c = tid & 3;
        const float gi = g[b * 17 + c] + bias2[c];
        const float gf = g[b * 17 + 4 + c] + bias2[4 + c];
        const float gg = g[b * 17 + 8 + c] + bias2[8 + c];
        const float go = g[b * 17 + 12 + c] + bias2[12 + c];
        const float cn = fsig(gf) * c2s[tid] + fsig(gi) * ftanh(gg);
        c2s[tid] = cn;
        p.h2b[(((unsigned)t & 1u) << 17) + (b << 10) + blk * 4 + c] = f2bf(fsig(go) * ftanh(cn));
      }
    }
    gbar(p.SY, round); ++round;
  }
  // final out_63
  if (blk >= 192) out_stage(p, g, 63, blk - 192);
}

// ---------------- prep kernels ----------------
__global__ __launch_bounds__(512) void k_zero(unsigned int* SY, float* q0) {
  SY[threadIdx.x] = 0u;
  q0[threadIdx.x] = 0.f;
}

__global__ __launch_bounds__(256) void k_cvt(const float* caps, const float* ench,
                                             const float* h1_0, const float* h2_0,
                                             unsigned short* o_caps, unsigned short* o_ench,
                                             unsigned short* o_h1, unsigned short* o_h2) {
  const size_t i = (size_t)blockIdx.x * 256 + threadIdx.x;
  if (i < 4194304u) o_caps[i] = f2bf(caps[i]);
  else if (i < 20971520u) o_ench[i - 4194304u] = f2bf(ench[i - 4194304u]);
  else if (i < 21102592u) o_h1[i - 20971520u] = f2bf(h1_0[i - 20971520u]);
  else o_h2[i - 21102592u] = f2bf(h2_0[i - 21102592u]);
}

// transpose+convert: out[r][k] = src(k)[col(r)], 4 out-rows x 64 k per block.
// perm: r = nb*16 + gg*4 + c  -> orig col = gg*1024 + nb*4 + c (gate-interleaved N tiles)
__global__ __launch_bounds__(256) void k_tr(const float* srcA, const float* srcB, int ksplit,
                                            int K, int stride, int Nrows, int perm,
                                            unsigned short* out, float* q0) {
  __shared__ float lds[64][5];
  const int nbr = Nrows >> 2;
  const int rt = blockIdx.x % nbr, kt = blockIdx.x / nbr;
  const int r0 = rt * 4, k0 = kt * 64;
  int oc0;
  if (perm) { const int nb = r0 >> 4, gg = (r0 & 15) >> 2; oc0 = gg * 1024 + nb * 4; }
  else oc0 = r0;
  {
    const int kk = threadIdx.x >> 2, rr = threadIdx.x & 3;
    const int k = k0 + kk;
    const float* s = (k < ksplit) ? (srcA + (size_t)k * stride) : (srcB + (size_t)(k - ksplit) * stride);
    lds[kk][rr] = s[oc0 + rr];
  }
  __syncthreads();
  if (q0 != nullptr && threadIdx.x < 4) {
    float t = 0.f;
    for (int kk = 0; kk < 64; ++kk) t += lds[kk][threadIdx.x];
    atomicAdd(&q0[oc0 + threadIdx.x], t);
  }
  {
    const int rr = threadIdx.x >> 6, kk = threadIdx.x & 63;
    out[(size_t)(r0 + rr) * K + k0 + kk] = f2bf(lds[kk][rr]);
  }
}

extern "C" void kernel_launch(void* const* d_in, const int* in_sizes, int n_in,
                              void* d_out, int out_size, void* d_ws, size_t ws_size,
                              hipStream_t stream) {
  const float* enc_hiddens = (const float*)d_in[0];
  const int*   enc_masks   = (const int*)d_in[1];
  const float* h1_0 = (const float*)d_in[2];
  const float* c1_0 = (const float*)d_in[3];
  const float* h2_0 = (const float*)d_in[4];
  const float* c2_0 = (const float*)d_in[5];
  const float* captions = (const float*)d_in[6];
  const float* att_W = (const float*)d_in[7];
  const float* att_b = (const float*)d_in[8];
  const float* dhp_W = (const float*)d_in[9];
  const float* dhp_b = (const float*)d_in[10];
  const float* corr_w = (const float*)d_in[11];
  const float* corr_b = (const float*)d_in[12];
  const float* lt_W = (const float*)d_in[13];
  const float* lt_b = (const float*)d_in[14];
  const float* W_ih1 = (const float*)d_in[15];
  const float* W_hh1 = (const float*)d_in[16];
  const float* b_ih1 = (const float*)d_in[17];
  const float* b_hh1 = (const float*)d_in[18];
  const float* W_ih2 = (const float*)d_in[19];
  const float* W_hh2 = (const float*)d_in[20];
  const float* b_ih2 = (const float*)d_in[21];
  const float* b_hh2 = (const float*)d_in[22];

  uint8_t* w = (uint8_t*)d_ws;
  unsigned int* SY = (unsigned int*)w;
  float* q0acc = (float*)(w + 2048);
  size_t off = 4096;
  unsigned short* ench  = (unsigned short*)(w + off); off += 33554432;  // (B,L,HE) bf16
  unsigned short* proj  = (unsigned short*)(w + off); off += 16777216;  // (B,L,AP) bf16
  unsigned short* caps  = (unsigned short*)(w + off); off += 8388608;   // (T,B,E) bf16
  unsigned short* W1t   = (unsigned short*)(w + off); off += 20971520;  // 4096x2560
  unsigned short* W2t   = (unsigned short*)(w + off); off += 16777216;  // 4096x2048
  unsigned short* dhpWt = (unsigned short*)(w + off); off += 1048576;   // 512x1024
  unsigned short* ltWt  = (unsigned short*)(w + off); off += 2097152;   // 1024x1024
  unsigned short* attWt = (unsigned short*)(w + off); off += 1048576;   // 512x1024
  unsigned short* at_   = (unsigned short*)(w + off); off += 262144;    // (B,1024) bf16
  unsigned short* h1b   = (unsigned short*)(w + off); off += 524288;    // 2 bufs
  unsigned short* h2b   = (unsigned short*)(w + off); off += 524288;    // 2 bufs
  float* qb             = (float*)(w + off);          off += 262144;    // (B,512) f32
  if (ws_size < off) return;  // insufficient workspace -> fail loudly via validation

  k_zero<<<1, 512, 0, stream>>>(SY, q0acc);
  k_cvt<<<82944, 256, 0, stream>>>(captions, enc_hiddens, h1_0, h2_0,
                                   caps, ench, h1b + 131072, h2b + 131072);
  k_tr<<<40960, 256, 0, stream>>>(W_ih1, W_hh1, 1536, 2560, 4096, 4096, 1, W1t, nullptr);
  k_tr<<<32768, 256, 0, stream>>>(W_ih2, W_hh2, 1024, 2048, 4096, 4096, 1, W2t, nullptr);
  k_tr<<<2048, 256, 0, stream>>>(dhp_W, dhp_W, 1024, 1024, 512, 512, 0, dhpWt, q0acc);
  k_tr<<<4096, 256, 0, stream>>>(lt_W, lt_W, 1024, 1024, 1024, 1024, 0, ltWt, nullptr);
  k_tr<<<2048, 256, 0, stream>>>(att_W, att_W, 1024, 1024, 512, 512, 0, attWt, nullptr);

  PP p;
  p.c1_0 = c1_0; p.c2_0 = c2_0;
  p.att_b = att_b; p.dhp_b = dhp_b; p.corr_w = corr_w; p.corr_b = corr_b; p.lt_b = lt_b;
  p.b_ih1 = b_ih1; p.b_hh1 = b_hh1; p.b_ih2 = b_ih2; p.b_hh2 = b_hh2;
  p.masks = enc_masks;
  p.out = (float*)d_out;
  p.SY = SY; p.q0acc = q0acc;
  p.ench = ench; p.proj = proj; p.caps = caps;
  p.W1t = W1t; p.W2t = W2t; p.dhpWt = dhpWt; p.ltWt = ltWt; p.attWt = attWt;
  p.at = at_; p.h1b = h1b; p.h2b = h2b; p.q = qb;

  persist<<<256, 1024, 0, stream>>>(p);
}

// Round 2
// 17420.782 us; speedup vs baseline: 1.0015x; 1.0015x over previous
//
#include <hip/hip_runtime.h>
#include <cstdint>
#include <cstddef>

#define DEVI __device__ __forceinline__

typedef __attribute__((ext_vector_type(8))) short short8;
typedef __attribute__((ext_vector_type(4))) float floatx4;

DEVI float bf2f(unsigned short u) { union { unsigned int i; float f; } v; v.i = ((unsigned int)u) << 16; return v.f; }
DEVI unsigned short f2bf(float f) {
  union { float f; unsigned int i; } v; v.f = f;
  unsigned int r = v.i + 0x7fffu + ((v.i >> 16) & 1u);
  return (unsigned short)(r >> 16);
}
DEVI float fsig(float x) { return 1.f / (1.f + __expf(-x)); }
DEVI float ftanh(float x) { return 1.f - 2.f / (__expf(2.f * x) + 1.f); }

// ---- agent-scope (cross-XCD coherent, L2-bypass) state accessors ----
DEVI unsigned ld32s(const unsigned* p) { return __hip_atomic_load(p, __ATOMIC_RELAXED, __HIP_MEMORY_SCOPE_AGENT); }
DEVI void st32s(unsigned* p, unsigned v) { __hip_atomic_store(p, v, __ATOMIC_RELAXED, __HIP_MEMORY_SCOPE_AGENT); }
DEVI unsigned long long ld64s(const void* p) { return __hip_atomic_load((const unsigned long long*)p, __ATOMIC_RELAXED, __HIP_MEMORY_SCOPE_AGENT); }
DEVI void st64s(void* p, unsigned long long v) { __hip_atomic_store((unsigned long long*)p, v, __ATOMIC_RELAXED, __HIP_MEMORY_SCOPE_AGENT); }
DEVI unsigned add32s(unsigned* p, unsigned v) { return __hip_atomic_fetch_add(p, v, __ATOMIC_RELAXED, __HIP_MEMORY_SCOPE_AGENT); }
DEVI short8 ld128s(const unsigned short* p) {
  union { unsigned long long u[2]; short8 s; } v;
  v.u[0] = ld64s(p); v.u[1] = ld64s(p + 4); return v.s;
}

struct PP {
  const float *c1_0, *c2_0;
  const float *att_b, *dhp_b, *corr_w, *corr_b, *lt_b;
  const float *b_ih1, *b_hh1, *b_ih2, *b_hh2;
  const int* masks;
  float* out;
  unsigned int* SY; float* q0acc;
  const unsigned short* ench; unsigned short* proj; const unsigned short* caps;
  const unsigned short *W1t, *W2t, *dhpWt, *ltWt, *attWt;
  unsigned short* at; unsigned short* h1b; unsigned short* h2b; float* q;
};

// ---- heavy barrier (L2 writeback+inv) — used ONCE after the preamble ----
DEVI void gbar_heavy(unsigned int* SY, int round) {
  __syncthreads();
  if (threadIdx.x == 0) {
    __threadfence();
    const int grp = blockIdx.x & 7;
    const unsigned v = add32s(&SY[16 + grp * 16], 1u);
    if (v == (unsigned)(round * 32 + 31)) {
      const unsigned w = add32s(&SY[0], 1u);
      if (w == (unsigned)(round * 8 + 7)) {
        __threadfence();
#pragma unroll
        for (int i = 0; i < 8; ++i) st32s(&SY[160 + i * 16], (unsigned)(round + 1));
      }
    }
    while (ld32s(&SY[160 + grp * 16]) < (unsigned)(round + 1)) __builtin_amdgcn_s_sleep(2);
    __threadfence();
  }
  __syncthreads();
}

// ---- light barrier: no cache maintenance. All state flows through sc1 ops. ----
DEVI void gbar(unsigned int* SY, int round) {
  __builtin_amdgcn_s_waitcnt(0);   // our sc1 stores have reached the coherent point
  __syncthreads();
  if (threadIdx.x == 0) {
    const int grp = blockIdx.x & 7;
    const unsigned v = add32s(&SY[16 + grp * 16], 1u);
    if (v == (unsigned)(round * 32 + 31)) {
      const unsigned w = add32s(&SY[0], 1u);
      if (w == (unsigned)(round * 8 + 7)) {
#pragma unroll
        for (int i = 0; i < 8; ++i) st32s(&SY[160 + i * 16], (unsigned)(round + 1));
      }
    }
    while (ld32s(&SY[160 + grp * 16]) < (unsigned)(round + 1)) __builtin_amdgcn_s_sleep(2);
  }
  __syncthreads();
}

DEVI void zero_g(float* g) {
  for (int i = threadIdx.x; i < 128 * 17; i += 1024) g[i] = 0.f;
}

// 16 waves = 16 K-slices (NS k-steps of 32 each) x all 8 M-tiles x this block's 16 N-cols.
// B-fragments live in registers (bf[NS]); partials combine via LDS fp32 atomics.
template <int NS, typename AL>
DEVI void gemm_reg(float* g, const short8* bf, AL aload) {
  const int tid = threadIdx.x, wave = tid >> 6, lane = tid & 63;
  const int kq = ((lane >> 4) << 3), m16 = lane & 15;
  const int k0w = wave * (NS << 5);
  floatx4 acc[8];
#pragma unroll
  for (int m = 0; m < 8; ++m) acc[m] = (floatx4){0.f, 0.f, 0.f, 0.f};
#pragma unroll
  for (int s = 0; s < NS; ++s) {
    const int k = k0w + (s << 5) + kq;
#pragma unroll
    for (int m = 0; m < 8; ++m) {
      short8 af = aload((m << 4) + m16, k);
      acc[m] = __builtin_amdgcn_mfma_f32_16x16x32_bf16(af, bf[s], acc[m], 0, 0, 0);
    }
  }
  const int col = m16, r0 = ((lane >> 4) << 2);
#pragma unroll
  for (int m = 0; m < 8; ++m)
#pragma unroll
    for (int r = 0; r < 4; ++r)
      atomicAdd(&g[((m << 4) + r0 + r) * 17 + col], acc[m][r]);
}

DEVI void out_stage(const PP& p, float* g, const short8* ltf, int ot, int ob) {
  zero_g(g); __syncthreads();
  const unsigned short* h1 = p.h1b + (((unsigned)ot & 1u) << 17);
  auto al = [&](int row, int k) -> short8 { return ld128s(h1 + ((size_t)row << 10) + k); };
  gemm_reg<2>(g, ltf, al);
  __syncthreads();
  for (int e = threadIdx.x; e < 2048; e += 1024) {
    const int b = e >> 4, col = e & 15, n = ob * 16 + col;
    p.out[(size_t)ot * 131072 + (b << 10) + n] = ftanh(g[b * 17 + col] + p.lt_b[n]);
  }
}

DEVI int qidx(int a) { return a + (a >> 6); }  // bank-conflict-free padding for 64-strided access

__global__ __launch_bounds__(1024) void persist(PP p) {
  __shared__ float g[128 * 17];
  __shared__ float c1s[512], c2s[512];
  __shared__ float bias1[16], bias2[16];
  __shared__ float q_ss[520], corr_ss[520];
  __shared__ float alpha_s[128], e_s[128];
  __shared__ int mask_s[128];
  __shared__ float redv[2];
  const int tid = threadIdx.x, blk = blockIdx.x;
  const int wave = tid >> 6, lane = tid & 63;
  const int kq = ((lane >> 4) << 3), m16 = lane & 15;

  // ---- per-wave register-resident weight fragments (live for the whole kernel) ----
  short8 w1f[5], w2f[4], ltf[2], dhpf[2];
  {
    const unsigned short* r1 = p.W1t + (size_t)(blk * 16 + m16) * 2560 + wave * 160 + kq;
#pragma unroll
    for (int s = 0; s < 5; ++s) w1f[s] = *(const short8*)(r1 + s * 32);
    const unsigned short* r2 = p.W2t + (size_t)(blk * 16 + m16) * 2048 + wave * 128 + kq;
#pragma unroll
    for (int s = 0; s < 4; ++s) w2f[s] = *(const short8*)(r2 + s * 32);
    if (blk >= 192) {
      const unsigned short* r3 = p.ltWt + (size_t)((blk - 192) * 16 + m16) * 1024 + wave * 64 + kq;
#pragma unroll
      for (int s = 0; s < 2; ++s) ltf[s] = *(const short8*)(r3 + s * 32);
    }
    if (blk < 32) {
      const unsigned short* r4 = p.dhpWt + (size_t)(blk * 16 + m16) * 1024 + wave * 64 + kq;
#pragma unroll
      for (int s = 0; s < 2; ++s) dhpf[s] = *(const short8*)(r4 + s * 32);
    }
  }

  // ---- preamble: enc_proj = ench @ att_W + att_b (plain stores; heavy barrier publishes) ----
  {
    const int mw = wave & 3, ng = wave >> 2;
    const int mtile = blk * 4 + mw;
    const int mrow = mtile * 16 + m16;
    floatx4 acc[8];
#pragma unroll
    for (int nt = 0; nt < 8; ++nt) acc[nt] = (floatx4){0.f, 0.f, 0.f, 0.f};
    for (int s = 0; s < 32; ++s) {
      const int k = (s << 5) + kq;
      short8 af = *(const short8*)(p.ench + (size_t)mrow * 1024 + k);
#pragma unroll
      for (int nt = 0; nt < 8; ++nt) {
        short8 bf = *(const short8*)(p.attWt + (size_t)(ng * 128 + nt * 16 + m16) * 1024 + k);
        acc[nt] = __builtin_amdgcn_mfma_f32_16x16x32_bf16(af, bf, acc[nt], 0, 0, 0);
      }
    }
#pragma unroll
    for (int nt = 0; nt < 8; ++nt)
#pragma unroll
      for (int r = 0; r < 4; ++r) {
        const int rowg = mtile * 16 + ((lane >> 4) << 2) + r;
        const int col = ng * 128 + nt * 16 + m16;
        p.proj[(size_t)rowg * 512 + col] = f2bf(acc[nt][r] + p.att_b[col]);
      }
  }
  if (blk < 128) {  // q for t=0: h_prev0 = ones/1024
    for (int n = tid; n < 512; n += 1024)
      p.q[blk * 512 + n] = p.q0acc[n] * (1.f / 1024.f) + p.dhp_b[n];
  }
  if (tid < 512) {
    const int b = tid >> 2, c = tid & 3;
    c1s[tid] = p.c1_0[b * 1024 + blk * 4 + c];
    c2s[tid] = p.c2_0[b * 1024 + blk * 4 + c];
  }
  if (tid < 16) {
    const int gg = tid >> 2, c = tid & 3;
    const int oc = gg * 1024 + blk * 4 + c;
    bias1[tid] = p.b_ih1[oc] + p.b_hh1[oc];
    bias2[tid] = p.b_ih2[oc] + p.b_hh2[oc];
  }
  if (blk >= 64 && blk < 192) {
    const int b = blk - 64;
    if (tid < 512) corr_ss[qidx(tid)] = p.corr_w[tid];
    if (tid < 128) mask_s[tid] = p.masks[b * 128 + tid];
  }

  int round = 0;
  gbar_heavy(p.SY, round); ++round;   // the ONLY cache-flushing barrier

  for (int t = 0; t < 64; ++t) {
    // ======== Stage 1: q_t (blk<32) | attention (blk 64..191) | out_{t-1} (blk>=192) ========
    if (blk < 32) {
      if (t > 0) {
        zero_g(g); __syncthreads();
        const unsigned short* h2p = p.h2b + ((((unsigned)t + 1u) & 1u) << 17);
        auto al = [&](int row, int k) -> short8 { return ld128s(h2p + ((size_t)row << 10) + k); };
        gemm_reg<2>(g, dhpf, al);
        __syncthreads();
        for (int e = tid; e < 2048; e += 1024) {
          const int b = e >> 4, col = e & 15, n = blk * 16 + col;
          const float qv = g[b * 17 + col] + p.dhp_b[n];
          const unsigned u = __float_as_uint(qv);
          const unsigned long long p4 =
              (unsigned long long)u |
              (((unsigned long long)(unsigned)__shfl_down((int)u, 1, 64)) << 32);
          if (!(e & 1)) st64s(p.q + b * 512 + n, p4);
        }
        __builtin_amdgcn_s_waitcnt(0);
        __syncthreads();
        if (tid == 0) add32s(&p.SY[300], 1u);
      }
    } else if (blk >= 64 && blk < 192) {
      const int b = blk - 64;
      if (t > 0) {
        if (tid == 0) {
          while (ld32s(&p.SY[300]) < (unsigned)(32 * t)) __builtin_amdgcn_s_sleep(2);
        }
        __syncthreads();
      }
      if (tid < 256) {
        const unsigned long long v = ld64s(p.q + b * 512 + tid * 2);
        q_ss[qidx(tid * 2)]     = __uint_as_float((unsigned)v);
        q_ss[qidx(tid * 2 + 1)] = __uint_as_float((unsigned)(v >> 32));
      }
      __syncthreads();
      {  // e[l] = corr . tanh(proj[b,l,:] + q); 8 lanes per l (plain cached proj reads)
        const int l = tid >> 3, l8 = tid & 7;
        const unsigned short* pp_ = p.proj + ((size_t)(b * 128 + l)) * 512 + l8 * 64;
        float acc = 0.f;
#pragma unroll 2
        for (int j = 0; j < 8; ++j) {
          short8 v = *(const short8*)(pp_ + j * 8);
#pragma unroll
          for (int i = 0; i < 8; ++i) {
            const int ap = l8 * 64 + j * 8 + i;
            acc += ftanh(bf2f((unsigned short)v[i]) + q_ss[qidx(ap)]) * corr_ss[qidx(ap)];
          }
        }
        acc += __shfl_down(acc, 4, 8);
        acc += __shfl_down(acc, 2, 8);
        acc += __shfl_down(acc, 1, 8);
        if (l8 == 0) {
          acc += p.corr_b[0];
          if (mask_s[l] != 0) acc = -1e30f;
          e_s[l] = acc;
        }
      }
      __syncthreads();
      if (wave == 0) {
        float m0 = fmaxf(e_s[lane], e_s[lane + 64]);
#pragma unroll
        for (int off = 32; off; off >>= 1) m0 = fmaxf(m0, __shfl_xor(m0, off));
        const float a0 = __expf(e_s[lane] - m0), a1 = __expf(e_s[lane + 64] - m0);
        alpha_s[lane] = a0; alpha_s[lane + 64] = a1;
        float s = a0 + a1;
#pragma unroll
        for (int off = 32; off; off >>= 1) s += __shfl_xor(s, off);
        if (lane == 0) redv[0] = 1.f / s;
      }
      __syncthreads();
      {  // a_t = alpha . ench (plain cached ench reads), sc1-packed stores
        const float inv = redv[0];
        const unsigned short* pe = p.ench + ((size_t)b << 17) + tid;
        float acc = 0.f;
#pragma unroll 4
        for (int l = 0; l < 128; ++l) acc += alpha_s[l] * bf2f(pe[(size_t)l << 10]);
        const unsigned short ab = f2bf(acc * inv);
        const unsigned p2 = (unsigned)ab |
                            (((unsigned)__shfl_down((int)(unsigned)ab, 1, 64)) << 16);
        if (!(tid & 1)) st32s((unsigned*)(p.at + (b << 10) + tid), p2);
      }
    } else if (blk >= 192) {
      if (t > 0) out_stage(p, g, ltf, t - 1, blk - 192);
    }
    gbar(p.SY, round); ++round;

    // ======== Stage 2: G1 = [x_t | a_t | h1_{t-1}] @ W1 -> LSTM1 (all blocks) ========
    {
      zero_g(g); __syncthreads();
      const unsigned short* caps_t = p.caps + ((size_t)t << 16);
      const unsigned short* h1p = p.h1b + ((((unsigned)t + 1u) & 1u) << 17);
      const unsigned short* at_ = p.at;
      auto al = [&](int row, int k) -> short8 {
        if (k < 512) return *(const short8*)(caps_t + ((size_t)row << 9) + k);
        if (k < 1536) return ld128s(at_ + ((size_t)row << 10) + (k - 512));
        return ld128s(h1p + ((size_t)row << 10) + (k - 1536));
      };
      gemm_reg<5>(g, w1f, al);
      __syncthreads();
      if (tid < 512) {
        const int b = tid >> 2, c = tid & 3;
        const float gi = g[b * 17 + c] + bias1[c];
        const float gf = g[b * 17 + 4 + c] + bias1[4 + c];
        const float gg = g[b * 17 + 8 + c] + bias1[8 + c];
        const float go = g[b * 17 + 12 + c] + bias1[12 + c];
        const float cn = fsig(gf) * c1s[tid] + fsig(gi) * ftanh(gg);
        c1s[tid] = cn;
        const unsigned short hv = f2bf(fsig(go) * ftanh(cn));
        const unsigned p2 = (unsigned)hv |
                            (((unsigned)__shfl_down((int)(unsigned)hv, 1, 64)) << 16);
        const unsigned long long p4 =
            (unsigned long long)p2 |
            (((unsigned long long)(unsigned)__shfl_down((int)p2, 2, 64)) << 32);
        if (c == 0)
          st64s(p.h1b + (((unsigned)t & 1u) << 17) + (b << 10) + blk * 4, p4);
      }
    }
    gbar(p.SY, round); ++round;

    // ======== Stage 3: G2 = [h1_t | h2_{t-1}] @ W2 -> LSTM2 (all blocks) ========
    {
      zero_g(g); __syncthreads();
      const unsigned short* h1c = p.h1b + (((unsigned)t & 1u) << 17);
      const unsigned short* h2p = p.h2b + ((((unsigned)t + 1u) & 1u) << 17);
      auto al = [&](int row, int k) -> short8 {
        if (k < 1024) return ld128s(h1c + ((size_t)row << 10) + k);
        return ld128s(h2p + ((size_t)row << 10) + (k - 1024));
      };
      gemm_reg<4>(g, w2f, al);
      __syncthreads();
      if (tid < 512) {
        const int b = tid >> 2, c = tid & 3;
        const float gi = g[b * 17 + c] + bias2[c];
        const float gf = g[b * 17 + 4 + c] + bias2[4 + c];
        const float gg = g[b * 17 + 8 + c] + bias2[8 + c];
        const float go = g[b * 17 + 12 + c] + bias2[12 + c];
        const float cn = fsig(gf) * c2s[tid] + fsig(gi) * ftanh(gg);
        c2s[tid] = cn;
        const unsigned short hv = f2bf(fsig(go) * ftanh(cn));
        const unsigned p2 = (unsigned)hv |
                            (((unsigned)__shfl_down((int)(unsigned)hv, 1, 64)) << 16);
        const unsigned long long p4 =
            (unsigned long long)p2 |
            (((unsigned long long)(unsigned)__shfl_down((int)p2, 2, 64)) << 32);
        if (c == 0)
          st64s(p.h2b + (((unsigned)t & 1u) << 17) + (b << 10) + blk * 4, p4);
      }
    }
    gbar(p.SY, round); ++round;
  }
  if (blk >= 192) out_stage(p, g, ltf, 63, blk - 192);
}

// ---------------- prep kernels ----------------
__global__ __launch_bounds__(512) void k_zero(unsigned int* SY, float* q0) {
  SY[threadIdx.x] = 0u;
  q0[threadIdx.x] = 0.f;
}

__global__ __launch_bounds__(256) void k_cvt(const float* caps, const float* ench,
                                             const float* h1_0, const float* h2_0,
                                             unsigned short* o_caps, unsigned short* o_ench,
                                             unsigned short* o_h1, unsigned short* o_h2) {
  const size_t i = (size_t)blockIdx.x * 256 + threadIdx.x;
  if (i < 4194304u) o_caps[i] = f2bf(caps[i]);
  else if (i < 20971520u) o_ench[i - 4194304u] = f2bf(ench[i - 4194304u]);
  else if (i < 21102592u) o_h1[i - 20971520u] = f2bf(h1_0[i - 20971520u]);
  else o_h2[i - 21102592u] = f2bf(h2_0[i - 21102592u]);
}

__global__ __launch_bounds__(256) void k_tr(const float* srcA, const float* srcB, int ksplit,
                                            int K, int stride, int Nrows, int perm,
                                            unsigned short* out, float* q0) {
  __shared__ float lds[64][5];
  const int nbr = Nrows >> 2;
  const int rt = blockIdx.x % nbr, kt = blockIdx.x / nbr;
  const int r0 = rt * 4, k0 = kt * 64;
  int oc0;
  if (perm) { const int nb = r0 >> 4, gg = (r0 & 15) >> 2; oc0 = gg * 1024 + nb * 4; }
  else oc0 = r0;
  {
    const int kk = threadIdx.x >> 2, rr = threadIdx.x & 3;
    const int k = k0 + kk;
    const float* s = (k < ksplit) ? (srcA + (size_t)k * stride) : (srcB + (size_t)(k - ksplit) * stride);
    lds[kk][rr] = s[oc0 + rr];
  }
  __syncthreads();
  if (q0 != nullptr && threadIdx.x < 4) {
    float t = 0.f;
    for (int kk = 0; kk < 64; ++kk) t += lds[kk][threadIdx.x];
    atomicAdd(&q0[oc0 + threadIdx.x], t);
  }
  {
    const int rr = threadIdx.x >> 6, kk = threadIdx.x & 63;
    out[(size_t)(r0 + rr) * K + k0 + kk] = f2bf(lds[kk][rr]);
  }
}

extern "C" void kernel_launch(void* const* d_in, const int* in_sizes, int n_in,
                              void* d_out, int out_size, void* d_ws, size_t ws_size,
                              hipStream_t stream) {
  const float* enc_hiddens = (const float*)d_in[0];
  const int*   enc_masks   = (const int*)d_in[1];
  const float* h1_0 = (const float*)d_in[2];
  const float* c1_0 = (const float*)d_in[3];
  const float* h2_0 = (const float*)d_in[4];
  const float* c2_0 = (const float*)d_in[5];
  const float* captions = (const float*)d_in[6];
  const float* att_W = (const float*)d_in[7];
  const float* att_b = (const float*)d_in[8];
  const float* dhp_W = (const float*)d_in[9];
  const float* dhp_b = (const float*)d_in[10];
  const float* corr_w = (const float*)d_in[11];
  const float* corr_b = (const float*)d_in[12];
  const float* lt_W = (const float*)d_in[13];
  const float* lt_b = (const float*)d_in[14];
  const float* W_ih1 = (const float*)d_in[15];
  const float* W_hh1 = (const float*)d_in[16];
  const float* b_ih1 = (const float*)d_in[17];
  const float* b_hh1 = (const float*)d_in[18];
  const float* W_ih2 = (const float*)d_in[19];
  const float* W_hh2 = (const float*)d_in[20];
  const float* b_ih2 = (const float*)d_in[21];
  const float* b_hh2 = (const float*)d_in[22];

  uint8_t* w = (uint8_t*)d_ws;
  unsigned int* SY = (unsigned int*)w;
  float* q0acc = (float*)(w + 2048);
  size_t off = 4096;
  unsigned short* ench  = (unsigned short*)(w + off); off += 33554432;
  unsigned short* proj  = (unsigned short*)(w + off); off += 16777216;
  unsigned short* caps  = (unsigned short*)(w + off); off += 8388608;
  unsigned short* W1t   = (unsigned short*)(w + off); off += 20971520;
  unsigned short* W2t   = (unsigned short*)(w + off); off += 16777216;
  unsigned short* dhpWt = (unsigned short*)(w + off); off += 1048576;
  unsigned short* ltWt  = (unsigned short*)(w + off); off += 2097152;
  unsigned short* attWt = (unsigned short*)(w + off); off += 1048576;
  unsigned short* at_   = (unsigned short*)(w + off); off += 262144;
  unsigned short* h1b   = (unsigned short*)(w + off); off += 524288;
  unsigned short* h2b   = (unsigned short*)(w + off); off += 524288;
  float* qb             = (float*)(w + off);          off += 262144;
  if (ws_size < off) return;

  k_zero<<<1, 512, 0, stream>>>(SY, q0acc);
  k_cvt<<<82944, 256, 0, stream>>>(captions, enc_hiddens, h1_0, h2_0,
                                   caps, ench, h1b + 131072, h2b + 131072);
  k_tr<<<40960, 256, 0, stream>>>(W_ih1, W_hh1, 1536, 2560, 4096, 4096, 1, W1t, nullptr);
  k_tr<<<32768, 256, 0, stream>>>(W_ih2, W_hh2, 1024, 2048, 4096, 4096, 1, W2t, nullptr);
  k_tr<<<2048, 256, 0, stream>>>(dhp_W, dhp_W, 1024, 1024, 512, 512, 0, dhpWt, q0acc);
  k_tr<<<4096, 256, 0, stream>>>(lt_W, lt_W, 1024, 1024, 1024, 1024, 0, ltWt, nullptr);
  k_tr<<<2048, 256, 0, stream>>>(att_W, att_W, 1024, 1024, 512, 512, 0, attWt, nullptr);

  PP p;
  p.c1_0 = c1_0; p.c2_0 = c2_0;
  p.att_b = att_b; p.dhp_b = dhp_b; p.corr_w = corr_w; p.corr_b = corr_b; p.lt_b = lt_b;
  p.b_ih1 = b_ih1; p.b_hh1 = b_hh1; p.b_ih2 = b_ih2; p.b_hh2 = b_hh2;
  p.masks = enc_masks;
  p.out = (float*)d_out;
  p.SY = SY; p.q0acc = q0acc;
  p.ench = ench; p.proj = proj; p.caps = caps;
  p.W1t = W1t; p.W2t = W2t; p.dhpWt = dhpWt; p.ltWt = ltWt; p.attWt = attWt;
  p.at = at_; p.h1b = h1b; p.h2b = h2b; p.q = qb;

  persist<<<256, 1024, 0, stream>>>(p);
}

// Round 3
// 12779.527 us; speedup vs baseline: 1.3652x; 1.3632x over previous
//
#include <hip/hip_runtime.h>
#include <cstdint>
#include <cstddef>

#define DEVI __device__ __forceinline__

typedef __attribute__((ext_vector_type(8))) short short8;
typedef __attribute__((ext_vector_type(4))) float floatx4;

DEVI float bf2f(unsigned short u) { union { unsigned int i; float f; } v; v.i = ((unsigned int)u) << 16; return v.f; }
DEVI unsigned short f2bf(float f) {
  union { float f; unsigned int i; } v; v.f = f;
  unsigned int r = v.i + 0x7fffu + ((v.i >> 16) & 1u);
  return (unsigned short)(r >> 16);
}
DEVI float fsig(float x) { return 1.f / (1.f + __expf(-x)); }
DEVI float ftanh(float x) { return 1.f - 2.f / (__expf(2.f * x) + 1.f); }

// agent-scope atomics: ONLY for the q->attention flag + q values inside k1
DEVI unsigned ld32s(const unsigned* p) { return __hip_atomic_load(p, __ATOMIC_RELAXED, __HIP_MEMORY_SCOPE_AGENT); }
DEVI void st32s(unsigned* p, unsigned v) { __hip_atomic_store(p, v, __ATOMIC_RELAXED, __HIP_MEMORY_SCOPE_AGENT); }
DEVI unsigned add32s(unsigned* p, unsigned v) { return __hip_atomic_fetch_add(p, v, __ATOMIC_RELAXED, __HIP_MEMORY_SCOPE_AGENT); }

struct PP {
  const float *c1_0, *c2_0;
  const float *att_b, *dhp_b, *corr_w, *corr_b, *lt_b;
  const float *b_ih1, *b_hh1, *b_ih2, *b_hh2;
  const int* masks;
  float* out;
  unsigned int* SY; float* q0acc;
  const unsigned short* ench; unsigned short* proj; const unsigned short* caps;
  const unsigned short *W1t, *W2t, *dhpWt, *ltWt, *attWt;
  unsigned short* at; unsigned short* h1b; unsigned short* h2b; float* q;
  float *c1ws, *c2ws;
};

DEVI void zero_g(float* g) {
  for (int i = threadIdx.x; i < 128 * 17; i += 1024) g[i] = 0.f;
}

// 16 waves = 16 K-slices (NS k-steps of 32) x 8 M-tiles x this tile's 16 N-cols.
// B loaded from Wrows (plain, per-lane row = lane&15); partials combined via LDS f32 atomics.
template <int NS, typename AL>
DEVI void gemm_g(float* g, const unsigned short* Wtile, int ldw, AL aload) {
  const int tid = threadIdx.x, wave = tid >> 6, lane = tid & 63;
  const int kq = ((lane >> 4) << 3), m16 = lane & 15;
  const int k0w = wave * (NS << 5);
  const unsigned short* wrow = Wtile + (size_t)m16 * ldw + k0w + kq;
  short8 bf[NS];
#pragma unroll
  for (int s = 0; s < NS; ++s) bf[s] = *(const short8*)(wrow + (s << 5));
  floatx4 acc[8];
#pragma unroll
  for (int m = 0; m < 8; ++m) acc[m] = (floatx4){0.f, 0.f, 0.f, 0.f};
#pragma unroll
  for (int s = 0; s < NS; ++s) {
    const int k = k0w + (s << 5) + kq;
#pragma unroll
    for (int m = 0; m < 8; ++m) {
      short8 af = aload((m << 4) + m16, k);
      acc[m] = __builtin_amdgcn_mfma_f32_16x16x32_bf16(af, bf[s], acc[m], 0, 0, 0);
    }
  }
  const int col = m16, r0 = ((lane >> 4) << 2);
#pragma unroll
  for (int m = 0; m < 8; ++m)
#pragma unroll
    for (int r = 0; r < 4; ++r)
      atomicAdd(&g[((m << 4) + r0 + r) * 17 + col], acc[m][r]);
}

DEVI int qidx(int a) { return a + (a >> 6); }

// ================= K1: q (blk<32) | attention (blk 32..159) | out_{t-1} (blk 160..223) =================
__global__ __launch_bounds__(1024, 4) void k1_attn(PP p, int t) {
  __shared__ float g[128 * 17];
  __shared__ float q_ss[520], corr_ss[520];
  __shared__ float alpha_s[128], e_s[128];
  __shared__ float redv[2];
  const int tid = threadIdx.x, blk = blockIdx.x;
  const int wave = tid >> 6, lane = tid & 63;

  if (blk < 32) {
    // ---- q_t = h2_{t-1} @ dhp_W + dhp_b (only 1<=t<64; t=0 uses precomputed init) ----
    if (t >= 1 && t < 64) {
      zero_g(g); __syncthreads();
      const unsigned short* h2p = p.h2b + ((((unsigned)t + 1u) & 1u) << 17);
      auto al = [&](int row, int k) -> short8 {
        return *(const short8*)(h2p + ((size_t)row << 10) + k);
      };
      gemm_g<2>(g, p.dhpWt + (size_t)blk * 16 * 1024, 1024, al);
      __syncthreads();
      for (int e = tid; e < 2048; e += 1024) {
        const int b = e >> 4, col = e & 15, n = blk * 16 + col;
        const float qv = g[b * 17 + col] + p.dhp_b[n];
        st32s((unsigned*)(p.q + b * 512 + n), __float_as_uint(qv));
      }
      __builtin_amdgcn_s_waitcnt(0);
    }
    __syncthreads();
    if (tid == 0) add32s(&p.SY[4], 1u);
  } else if (blk < 160) {
    // ---- attention for batch b ----
    if (t < 64) {
      const int b = blk - 32;
      if (t >= 1) {
        if (tid == 0) {
          while (ld32s(&p.SY[4]) < (unsigned)(32 * (t + 1))) __builtin_amdgcn_s_sleep(1);
        }
        __syncthreads();
        if (tid < 512) q_ss[qidx(tid)] = __uint_as_float(ld32s((const unsigned*)(p.q + b * 512 + tid)));
      } else {
        if (tid < 512) q_ss[qidx(tid)] = p.q[b * 512 + tid];
      }
      if (tid < 512) corr_ss[qidx(tid)] = p.corr_w[tid];
      __syncthreads();
      {  // e[l] = corr . tanh(proj[b,l,:] + q): 8 lanes per l; batch all loads first
        const int l = tid >> 3, l8 = tid & 7;
        const unsigned short* pp_ = p.proj + ((size_t)(b * 128 + l)) * 512 + l8 * 64;
        short8 vv[8];
#pragma unroll
        for (int j = 0; j < 8; ++j) vv[j] = *(const short8*)(pp_ + j * 8);
        float acc = 0.f;
#pragma unroll
        for (int j = 0; j < 8; ++j)
#pragma unroll
          for (int i = 0; i < 8; ++i) {
            const int ap = l8 * 64 + j * 8 + i;
            acc += ftanh(bf2f((unsigned short)vv[j][i]) + q_ss[qidx(ap)]) * corr_ss[qidx(ap)];
          }
        acc += __shfl_down(acc, 4, 8);
        acc += __shfl_down(acc, 2, 8);
        acc += __shfl_down(acc, 1, 8);
        if (l8 == 0) {
          acc += p.corr_b[0];
          if (p.masks[b * 128 + l] != 0) acc = -1e30f;
          e_s[l] = acc;
        }
      }
      __syncthreads();
      if (wave == 0) {
        float m0 = fmaxf(e_s[lane], e_s[lane + 64]);
#pragma unroll
        for (int off = 32; off; off >>= 1) m0 = fmaxf(m0, __shfl_xor(m0, off));
        const float a0 = __expf(e_s[lane] - m0), a1 = __expf(e_s[lane + 64] - m0);
        alpha_s[lane] = a0; alpha_s[lane + 64] = a1;
        float s = a0 + a1;
#pragma unroll
        for (int off = 32; off; off >>= 1) s += __shfl_xor(s, off);
        if (lane == 0) redv[0] = 1.f / s;
      }
      __syncthreads();
      {  // a_t[c] = sum_l alpha[l] * ench[b,l,c]; deep unroll for MLP; PLAIN store
        const float inv = redv[0];
        const unsigned short* pe = p.ench + ((size_t)b << 17) + tid;
        float acc = 0.f;
#pragma unroll 16
        for (int l = 0; l < 128; ++l) acc += alpha_s[l] * bf2f(pe[(size_t)l << 10]);
        p.at[(b << 10) + tid] = f2bf(acc * inv);
      }
    }
  } else {
    // ---- out_{t-1} = tanh(h1_{t-1} @ lt_W + lt_b) (t>=1) ----
    if (t >= 1) {
      const int ob = blk - 160, ot = t - 1;
      zero_g(g); __syncthreads();
      const unsigned short* h1 = p.h1b + (((unsigned)ot & 1u) << 17);
      auto al = [&](int row, int k) -> short8 {
        return *(const short8*)(h1 + ((size_t)row << 10) + k);
      };
      gemm_g<2>(g, p.ltWt + (size_t)ob * 16 * 1024, 1024, al);
      __syncthreads();
      for (int e = tid; e < 2048; e += 1024) {
        const int b = e >> 4, col = e & 15, n = ob * 16 + col;
        p.out[(size_t)ot * 131072 + (b << 10) + n] = ftanh(g[b * 17 + col] + p.lt_b[n]);
      }
    }
  }
}

// ================= K2: G1 = [x_t | a_t | h1_{t-1}] @ W1 -> LSTM1 =================
__global__ __launch_bounds__(1024, 4) void k2_g1(PP p, int t) {
  __shared__ float g[128 * 17];
  const int tid = threadIdx.x, blk = blockIdx.x;
  zero_g(g); __syncthreads();
  const unsigned short* caps_t = p.caps + ((size_t)t << 16);
  const unsigned short* h1p = p.h1b + ((((unsigned)t + 1u) & 1u) << 17);
  const unsigned short* at_ = p.at;
  auto al = [&](int row, int k) -> short8 {
    if (k < 512) return *(const short8*)(caps_t + ((size_t)row << 9) + k);
    if (k < 1536) return *(const short8*)(at_ + ((size_t)row << 10) + (k - 512));
    return *(const short8*)(h1p + ((size_t)row << 10) + (k - 1536));
  };
  gemm_g<5>(g, p.W1t + (size_t)blk * 16 * 2560, 2560, al);
  __syncthreads();
  if (tid < 512) {
    const int b = tid >> 2, c = tid & 3;
    const int cidx = b * 1024 + blk * 4 + c;
    const float cprev = (t == 0) ? p.c1_0[cidx] : p.c1ws[cidx];
    const float gi = g[b * 17 + c]      + p.b_ih1[blk * 4 + c]        + p.b_hh1[blk * 4 + c];
    const float gf = g[b * 17 + 4 + c]  + p.b_ih1[1024 + blk * 4 + c] + p.b_hh1[1024 + blk * 4 + c];
    const float gg = g[b * 17 + 8 + c]  + p.b_ih1[2048 + blk * 4 + c] + p.b_hh1[2048 + blk * 4 + c];
    const float go = g[b * 17 + 12 + c] + p.b_ih1[3072 + blk * 4 + c] + p.b_hh1[3072 + blk * 4 + c];
    const float cn = fsig(gf) * cprev + fsig(gi) * ftanh(gg);
    p.c1ws[cidx] = cn;
    p.h1b[(((unsigned)t & 1u) << 17) + (b << 10) + blk * 4 + c] = f2bf(fsig(go) * ftanh(cn));
  }
}

// ================= K3: G2 = [h1_t | h2_{t-1}] @ W2 -> LSTM2 =================
__global__ __launch_bounds__(1024, 4) void k3_g2(PP p, int t) {
  __shared__ float g[128 * 17];
  const int tid = threadIdx.x, blk = blockIdx.x;
  zero_g(g); __syncthreads();
  const unsigned short* h1c = p.h1b + (((unsigned)t & 1u) << 17);
  const unsigned short* h2p = p.h2b + ((((unsigned)t + 1u) & 1u) << 17);
  auto al = [&](int row, int k) -> short8 {
    if (k < 1024) return *(const short8*)(h1c + ((size_t)row << 10) + k);
    return *(const short8*)(h2p + ((size_t)row << 10) + (k - 1024));
  };
  gemm_g<4>(g, p.W2t + (size_t)blk * 16 * 2048, 2048, al);
  __syncthreads();
  if (tid < 512) {
    const int b = tid >> 2, c = tid & 3;
    const int cidx = b * 1024 + blk * 4 + c;
    const float cprev = (t == 0) ? p.c2_0[cidx] : p.c2ws[cidx];
    const float gi = g[b * 17 + c]      + p.b_ih2[blk * 4 + c]        + p.b_hh2[blk * 4 + c];
    const float gf = g[b * 17 + 4 + c]  + p.b_ih2[1024 + blk * 4 + c] + p.b_hh2[1024 + blk * 4 + c];
    const float gg = g[b * 17 + 8 + c]  + p.b_ih2[2048 + blk * 4 + c] + p.b_hh2[2048 + blk * 4 + c];
    const float go = g[b * 17 + 12 + c] + p.b_ih2[3072 + blk * 4 + c] + p.b_hh2[3072 + blk * 4 + c];
    const float cn = fsig(gf) * cprev + fsig(gi) * ftanh(gg);
    p.c2ws[cidx] = cn;
    p.h2b[(((unsigned)t & 1u) << 17) + (b << 10) + blk * 4 + c] = f2bf(fsig(go) * ftanh(cn));
  }
}

// ================= prep =================
__global__ __launch_bounds__(512) void k_zero(unsigned int* SY, float* q0) {
  SY[threadIdx.x] = 0u;
  q0[threadIdx.x] = 0.f;
}

__global__ __launch_bounds__(256) void k_cvt(const float* caps, const float* ench,
                                             const float* h1_0, const float* h2_0,
                                             unsigned short* o_caps, unsigned short* o_ench,
                                             unsigned short* o_h1, unsigned short* o_h2) {
  const size_t i = (size_t)blockIdx.x * 256 + threadIdx.x;
  if (i < 4194304u) o_caps[i] = f2bf(caps[i]);
  else if (i < 20971520u) o_ench[i - 4194304u] = f2bf(ench[i - 4194304u]);
  else if (i < 21102592u) o_h1[i - 20971520u] = f2bf(h1_0[i - 20971520u]);
  else o_h2[i - 21102592u] = f2bf(h2_0[i - 21102592u]);
}

__global__ __launch_bounds__(256) void k_tr(const float* srcA, const float* srcB, int ksplit,
                                            int K, int stride, int Nrows, int perm,
                                            unsigned short* out, float* q0) {
  __shared__ float lds[64][5];
  const int nbr = Nrows >> 2;
  const int rt = blockIdx.x % nbr, kt = blockIdx.x / nbr;
  const int r0 = rt * 4, k0 = kt * 64;
  int oc0;
  if (perm) { const int nb = r0 >> 4, gg = (r0 & 15) >> 2; oc0 = gg * 1024 + nb * 4; }
  else oc0 = r0;
  {
    const int kk = threadIdx.x >> 2, rr = threadIdx.x & 3;
    const int k = k0 + kk;
    const float* s = (k < ksplit) ? (srcA + (size_t)k * stride) : (srcB + (size_t)(k - ksplit) * stride);
    lds[kk][rr] = s[oc0 + rr];
  }
  __syncthreads();
  if (q0 != nullptr && threadIdx.x < 4) {
    float t = 0.f;
    for (int kk = 0; kk < 64; ++kk) t += lds[kk][threadIdx.x];
    atomicAdd(&q0[oc0 + threadIdx.x], t);
  }
  {
    const int rr = threadIdx.x >> 6, kk = threadIdx.x & 63;
    out[(size_t)(r0 + rr) * K + k0 + kk] = f2bf(lds[kk][rr]);
  }
}

// enc_proj = ench @ att_W + att_b
__global__ __launch_bounds__(1024, 4) void k_proj(PP p) {
  const int tid = threadIdx.x, blk = blockIdx.x;
  const int wave = tid >> 6, lane = tid & 63;
  const int kq = ((lane >> 4) << 3), m16 = lane & 15;
  const int mw = wave & 3, ng = wave >> 2;
  const int mtile = blk * 4 + mw;
  const int mrow = mtile * 16 + m16;
  floatx4 acc[8];
#pragma unroll
  for (int nt = 0; nt < 8; ++nt) acc[nt] = (floatx4){0.f, 0.f, 0.f, 0.f};
  for (int s = 0; s < 32; ++s) {
    const int k = (s << 5) + kq;
    short8 af = *(const short8*)(p.ench + (size_t)mrow * 1024 + k);
#pragma unroll
    for (int nt = 0; nt < 8; ++nt) {
      short8 bf = *(const short8*)(p.attWt + (size_t)(ng * 128 + nt * 16 + m16) * 1024 + k);
      acc[nt] = __builtin_amdgcn_mfma_f32_16x16x32_bf16(af, bf, acc[nt], 0, 0, 0);
    }
  }
#pragma unroll
  for (int nt = 0; nt < 8; ++nt)
#pragma unroll
    for (int r = 0; r < 4; ++r) {
      const int rowg = mtile * 16 + ((lane >> 4) << 2) + r;
      const int col = ng * 128 + nt * 16 + m16;
      p.proj[(size_t)rowg * 512 + col] = f2bf(acc[nt][r] + p.att_b[col]);
    }
}

__global__ __launch_bounds__(1024) void k_qinit(float* q, const float* q0acc, const float* dhp_b) {
  const int i = blockIdx.x * 1024 + threadIdx.x;  // 65536
  const int n = i & 511;
  q[i] = q0acc[n] * (1.f / 1024.f) + dhp_b[n];
}

extern "C" void kernel_launch(void* const* d_in, const int* in_sizes, int n_in,
                              void* d_out, int out_size, void* d_ws, size_t ws_size,
                              hipStream_t stream) {
  const float* enc_hiddens = (const float*)d_in[0];
  const int*   enc_masks   = (const int*)d_in[1];
  const float* h1_0 = (const float*)d_in[2];
  const float* c1_0 = (const float*)d_in[3];
  const float* h2_0 = (const float*)d_in[4];
  const float* c2_0 = (const float*)d_in[5];
  const float* captions = (const float*)d_in[6];
  const float* att_W = (const float*)d_in[7];
  const float* att_b = (const float*)d_in[8];
  const float* dhp_W = (const float*)d_in[9];
  const float* dhp_b = (const float*)d_in[10];
  const float* corr_w = (const float*)d_in[11];
  const float* corr_b = (const float*)d_in[12];
  const float* lt_W = (const float*)d_in[13];
  const float* lt_b = (const float*)d_in[14];
  const float* W_ih1 = (const float*)d_in[15];
  const float* W_hh1 = (const float*)d_in[16];
  const float* b_ih1 = (const float*)d_in[17];
  const float* b_hh1 = (const float*)d_in[18];
  const float* W_ih2 = (const float*)d_in[19];
  const float* W_hh2 = (const float*)d_in[20];
  const float* b_ih2 = (const float*)d_in[21];
  const float* b_hh2 = (const float*)d_in[22];

  uint8_t* w = (uint8_t*)d_ws;
  unsigned int* SY = (unsigned int*)w;
  float* q0acc = (float*)(w + 2048);
  size_t off = 4096;
  unsigned short* ench  = (unsigned short*)(w + off); off += 33554432;
  unsigned short* proj  = (unsigned short*)(w + off); off += 16777216;
  unsigned short* caps  = (unsigned short*)(w + off); off += 8388608;
  unsigned short* W1t   = (unsigned short*)(w + off); off += 20971520;
  unsigned short* W2t   = (unsigned short*)(w + off); off += 16777216;
  unsigned short* dhpWt = (unsigned short*)(w + off); off += 1048576;
  unsigned short* ltWt  = (unsigned short*)(w + off); off += 2097152;
  unsigned short* attWt = (unsigned short*)(w + off); off += 1048576;
  unsigned short* at_   = (unsigned short*)(w + off); off += 262144;
  unsigned short* h1b   = (unsigned short*)(w + off); off += 524288;
  unsigned short* h2b   = (unsigned short*)(w + off); off += 524288;
  float* qb             = (float*)(w + off);          off += 262144;
  float* c1ws           = (float*)(w + off);          off += 524288;
  float* c2ws           = (float*)(w + off);          off += 524288;
  if (ws_size < off) return;

  k_zero<<<1, 512, 0, stream>>>(SY, q0acc);
  k_cvt<<<82944, 256, 0, stream>>>(captions, enc_hiddens, h1_0, h2_0,
                                   caps, ench, h1b + 131072, h2b + 131072);
  k_tr<<<40960, 256, 0, stream>>>(W_ih1, W_hh1, 1536, 2560, 4096, 4096, 1, W1t, nullptr);
  k_tr<<<32768, 256, 0, stream>>>(W_ih2, W_hh2, 1024, 2048, 4096, 4096, 1, W2t, nullptr);
  k_tr<<<2048, 256, 0, stream>>>(dhp_W, dhp_W, 1024, 1024, 512, 512, 0, dhpWt, q0acc);
  k_tr<<<4096, 256, 0, stream>>>(lt_W, lt_W, 1024, 1024, 1024, 1024, 0, ltWt, nullptr);
  k_tr<<<2048, 256, 0, stream>>>(att_W, att_W, 1024, 1024, 512, 512, 0, attWt, nullptr);
  k_qinit<<<64, 1024, 0, stream>>>(qb, q0acc, dhp_b);

  PP p;
  p.c1_0 = c1_0; p.c2_0 = c2_0;
  p.att_b = att_b; p.dhp_b = dhp_b; p.corr_w = corr_w; p.corr_b = corr_b; p.lt_b = lt_b;
  p.b_ih1 = b_ih1; p.b_hh1 = b_hh1; p.b_ih2 = b_ih2; p.b_hh2 = b_hh2;
  p.masks = enc_masks;
  p.out = (float*)d_out;
  p.SY = SY; p.q0acc = q0acc;
  p.ench = ench; p.proj = proj; p.caps = caps;
  p.W1t = W1t; p.W2t = W2t; p.dhpWt = dhpWt; p.ltWt = ltWt; p.attWt = attWt;
  p.at = at_; p.h1b = h1b; p.h2b = h2b; p.q = qb;
  p.c1ws = c1ws; p.c2ws = c2ws;

  k_proj<<<256, 1024, 0, stream>>>(p);

  for (int t = 0; t < 64; ++t) {
    k1_attn<<<224, 1024, 0, stream>>>(p, t);
    k2_g1<<<256, 1024, 0, stream>>>(p, t);
    k3_g2<<<256, 1024, 0, stream>>>(p, t);
  }
  k1_attn<<<224, 1024, 0, stream>>>(p, 64);  // final out_63
}